// Round 7
// baseline (189.231 us; speedup 1.0000x reference)
//
#include <hip/hip_runtime.h>

#define BB 16
#define SS 2048
#define NTOK (BB*SS)
#define NPAIR (NTOK/2)
#define PLANE (NPAIR*4)
#define FF 512
#define EPSF 1e-5f
#define QW 16

#if __has_builtin(__builtin_amdgcn_exp2f)
#define EXP2F(x) __builtin_amdgcn_exp2f(x)
#else
#define EXP2F(x) exp2f(x)
#endif

typedef float v2f __attribute__((ext_vector_type(2)));

// ---------------- ws float layout ----------------
// sm   : [L][64]        fused small mats (exp2-prescaled)  @ 0        (128)
// w1t  : [L][512][12]   {w1col[4], w2row[4], b1, pad3}     @ 128      (12288)
// X1   : [NTOK][4]                                         @ 12416    (131072)
// f0   : [5][NPAIR][4]  pair-interleaved SoA planes        @ 143488   (327680)
// f1   : same                                              @ 471168   (327680)

__device__ __forceinline__ float wred64(float v) {
#pragma unroll
  for (int m = 32; m > 0; m >>= 1) v += __shfl_xor(v, m, 64);
  return v;
}

__device__ __forceinline__ float rflf(float v) {
  union { float f; int i; } u; u.f = v;
  u.i = __builtin_amdgcn_readfirstlane(u.i);
  return u.f;
}

// sm layout (per layer, stride 64):
// 0:M4[16] (bw2*Wq^T Wk)   16:Bk[16] (-.5 bw2 Wk^T Wk)   32:WVO[16] (Wv*Wo)
// 48:ak[4]  52:bvo[4]  56:ck      where bw2 = bw^2 * log2(e)

__global__ __launch_bounds__(64) void prep_kernel(
    const float* __restrict__ Wq, const float* __restrict__ bq,
    const float* __restrict__ Wk, const float* __restrict__ bk,
    const float* __restrict__ Wv, const float* __restrict__ bv,
    const float* __restrict__ Wo, const float* __restrict__ bw,
    const float* __restrict__ W1, const float* __restrict__ b1,
    const float* __restrict__ W2,
    float* __restrict__ sm, float* __restrict__ w1t)
{
  const int i = blockIdx.x;       // layer
  const int lane = threadIdx.x;   // 0..63
  float m4[4][4] = {{0}}, gkk[4][4] = {{0}}, wvo[4][4] = {{0}};
  float akk[4] = {0}, bvo[4] = {0};
  float ck1 = 0.f, ck2 = 0.f;

  for (int h = lane; h < 256; h += 64) {
    float vq[4], vk[4], vv[4], wo4[4];
#pragma unroll
    for (int a = 0; a < 4; ++a) {
      vq[a]  = Wq[(i*4 + a)*256 + h];
      vk[a]  = Wk[(i*4 + a)*256 + h];
      vv[a]  = Wv[(i*4 + a)*256 + h];
      wo4[a] = Wo[(i*256 + h)*4 + a];
    }
    const float bqh = bq[i*256 + h], bkh = bk[i*256 + h], bvh = bv[i*256 + h];
#pragma unroll
    for (int a = 0; a < 4; ++a) {
#pragma unroll
      for (int c = 0; c < 4; ++c) {
        m4[a][c]  = fmaf(vq[a], vk[c], m4[a][c]);
        gkk[a][c] = fmaf(vk[a], vk[c], gkk[a][c]);
        wvo[a][c] = fmaf(vv[a], wo4[c], wvo[a][c]);
      }
      akk[a] = fmaf(vk[a], bqh - bkh, akk[a]);
      bvo[a] = fmaf(bvh, wo4[a], bvo[a]);
    }
    ck1 = fmaf(bqh, bkh, ck1);
    ck2 = fmaf(bkh, bkh, ck2);
  }
#pragma unroll
  for (int a = 0; a < 4; ++a) {
#pragma unroll
    for (int c = 0; c < 4; ++c) {
      m4[a][c]  = wred64(m4[a][c]);
      gkk[a][c] = wred64(gkk[a][c]);
      wvo[a][c] = wred64(wvo[a][c]);
    }
    akk[a] = wred64(akk[a]);
    bvo[a] = wred64(bvo[a]);
  }
  ck1 = wred64(ck1); ck2 = wred64(ck2);

  if (lane == 0) {
    const float bwv = bw[i];
    const float bw2 = bwv * bwv * 1.44269504088896f;   // exp2 prescale
    float* s = sm + i*64;
#pragma unroll
    for (int a = 0; a < 4; ++a) {
#pragma unroll
      for (int c = 0; c < 4; ++c) {
        s[a*4+c]      = bw2 * m4[a][c];
        s[16 + a*4+c] = -0.5f * bw2 * gkk[a][c];
        s[32 + a*4+c] = wvo[a][c];
      }
      s[48+a] = bw2 * akk[a];
      s[52+a] = bvo[a];
    }
    s[56] = bw2 * (ck1 - 0.5f * ck2);
  }
  // FFN weight repack: w1t[f] = {W1[:,f], W2[f,:], b1[f], pad}
  for (int f = lane; f < FF; f += 64) {
    float* rec = w1t + (i*FF + f)*12;
#pragma unroll
    for (int c = 0; c < 4; ++c) rec[c]   = W1[(i*4 + c)*FF + f];
#pragma unroll
    for (int c = 0; c < 4; ++c) rec[4+c] = W2[(i*FF + f)*4 + c];
    rec[8] = b1[i*FF + f];
    rec[9] = 0.f; rec[10] = 0.f; rec[11] = 0.f;
  }
}

// feat record: {P[4], VT[4], R}; query-side constant dropped (cancels in softmax)
__device__ __forceinline__ void compute_feat(const float x[4], const float* __restrict__ s,
                                             float* __restrict__ featrec)
{
  float P[4], VT[4], tk[4];
#pragma unroll
  for (int a = 0; a < 4; ++a) {
    P[a]  = fmaf(s[a*4+3], x[3], fmaf(s[a*4+2], x[2], fmaf(s[a*4+1], x[1], s[a*4+0]*x[0])));
    tk[a] = fmaf(s[16+a*4+3], x[3], fmaf(s[16+a*4+2], x[2], fmaf(s[16+a*4+1], x[1], s[16+a*4+0]*x[0])));
    VT[a] = s[52+a] + fmaf(s[32+3*4+a], x[3], fmaf(s[32+2*4+a], x[2], fmaf(s[32+1*4+a], x[1], s[32+0*4+a]*x[0])));
  }
  float R = s[56];
#pragma unroll
  for (int a = 0; a < 4; ++a) R = fmaf(tk[a] + s[48+a], x[a], R);
  featrec[0]=P[0]; featrec[1]=P[1]; featrec[2]=P[2]; featrec[3]=P[3];
  featrec[4]=VT[0]; featrec[5]=VT[1]; featrec[6]=VT[2]; featrec[7]=VT[3];
  featrec[8]=R;
}

// layer-0 key features -> pair-interleaved SoA planes. thread = pair (2 tokens).
__global__ __launch_bounds__(256) void feat_kernel(
    const float* __restrict__ KEY, const float* __restrict__ VALUE,
    const float* __restrict__ sm, float* __restrict__ feat)
{
  const int p = blockIdx.x*256 + threadIdx.x;       // pair index
  const int ta = 2*p, tb = 2*p + 1;
  float xa[4] = {KEY[ta*3], KEY[ta*3+1], KEY[ta*3+2], VALUE[ta]};
  float xb[4] = {KEY[tb*3], KEY[tb*3+1], KEY[tb*3+2], VALUE[tb]};
  float fa[9], fb[9];
  compute_feat(xa, sm, fa);
  compute_feat(xb, sm, fb);
#pragma unroll
  for (int pl = 0; pl < 4; ++pl) {
    *(float4*)(feat + (size_t)pl*PLANE + (size_t)p*4) =
        make_float4(fa[2*pl], fb[2*pl], fa[2*pl+1], fb[2*pl+1]);
  }
  *(float4*)(feat + (size_t)4*PLANE + (size_t)p*4) =
      make_float4(fa[8], fb[8], 0.f, 0.f);
}

__device__ __forceinline__ void ln4(const float t[4], const float* __restrict__ g,
                                    const float* __restrict__ b, float r[4])
{
  const float m = 0.25f*(t[0]+t[1]+t[2]+t[3]);
  const float d0 = t[0]-m, d1 = t[1]-m, d2 = t[2]-m, d3 = t[3]-m;
  const float v = 0.25f*(d0*d0 + d1*d1 + d2*d2 + d3*d3);
  const float sc = rsqrtf(v + EPSF);
  r[0] = fmaf(d0*sc, g[0], b[0]);
  r[1] = fmaf(d1*sc, g[1], b[1]);
  r[2] = fmaf(d2*sc, g[2], b[2]);
  r[3] = fmaf(d3*sc, g[3], b[3]);
}

// Flipped-dataflow fused layer kernel, 16 q/wave: block = 256 thr (4 waves),
// 64 queries/block, grid 512 (2 blocks/CU). Wave owns 16 queries in SGPRs and
// streams all 2048 keys of its batch (2 keys/lane from pair-interleaved planes,
// coalesced float4, zero LDS / broadcast / barriers in the main loop).
// Manual ping-pong prefetch (named A/B buffers, no runtime-indexed arrays).
// acc = 16q x 5 v2f = 160 VGPR; __launch_bounds__(256,2) -> 256-VGPR cap, no spill.
// Epilogue: horizontal add + wave butterfly, LN1, FFN (4 fc x 128 f), LN2.
__global__ __launch_bounds__(256, 2) void layer_kernel(
    const float* __restrict__ KEY, const float* __restrict__ VALUE,
    const float* __restrict__ X, const float* __restrict__ feat,
    const float* __restrict__ w1t, const float* __restrict__ smn,
    const float* __restrict__ bo, const float* __restrict__ g1, const float* __restrict__ be1,
    const float* __restrict__ b2v, const float* __restrict__ g2, const float* __restrict__ be2,
    float* __restrict__ Xout, float* __restrict__ featout,
    const float* __restrict__ Wfc, const float* __restrict__ bfc,
    float* __restrict__ outp, int first, int last)
{
  const int bid = blockIdx.x;                  // 512 blocks
  const int b = bid >> 5, qg = bid & 31;
  const int qbase = (b << 11) + (qg << 6);     // 64 queries per block
  const int tid = threadIdx.x;
  const int lane = tid & 63, wv = tid >> 6;    // wave 0..3
  const int q0 = qbase + wv*QW;                // this wave's 16 queries

  __shared__ float sums[4*QW*9];   // [wave][q][9]
  __shared__ float ress[64*4];
  __shared__ float redf[4*64*4];

  // 16 queries -> SGPRs (uniform loads + readfirstlane)
  float qx0[QW], qx1[QW], qx2[QW], qx3[QW];
#pragma unroll
  for (int q = 0; q < QW; ++q) {
    const int gq = q0 + q;
    float a, b_, c, d;
    if (first) {
      a = KEY[gq*3]; b_ = KEY[gq*3+1]; c = KEY[gq*3+2]; d = VALUE[gq];
    } else {
      const float4 xv = *(const float4*)(X + (size_t)gq*4);
      a = xv.x; b_ = xv.y; c = xv.z; d = xv.w;
    }
    qx0[q] = rflf(a); qx1[q] = rflf(b_); qx2[q] = rflf(c); qx3[q] = rflf(d);
  }

  v2f aV0[QW], aV1[QW], aV2[QW], aV3[QW], aD[QW];
#pragma unroll
  for (int q = 0; q < QW; ++q) {
    aV0[q] = v2f{0.f,0.f}; aV1[q] = v2f{0.f,0.f};
    aV2[q] = v2f{0.f,0.f}; aV3[q] = v2f{0.f,0.f};
    aD[q]  = v2f{0.f,0.f};
  }

  const int pb = (b << 10) + lane;             // batch pair base + lane

  // process one 5-plane record pair against all 16 queries (pure VALU)
  auto PROC = [&](const float4& A, const float4& Bf, const float4& C,
                  const float4& D, const float4& E) {
    const v2f P0 = v2f{A.x, A.y},   P1 = v2f{A.z, A.w};
    const v2f P2 = v2f{Bf.x, Bf.y}, P3 = v2f{Bf.z, Bf.w};
    const v2f V0 = v2f{C.x, C.y},   V1 = v2f{C.z, C.w};
    const v2f V2 = v2f{D.x, D.y},   V3 = v2f{D.z, D.w};
    const v2f Rp = v2f{E.x, E.y};
#pragma unroll
    for (int q = 0; q < QW; ++q) {
      v2f l = __builtin_elementwise_fma(P0, v2f{qx0[q], qx0[q]}, Rp);
      l = __builtin_elementwise_fma(P1, v2f{qx1[q], qx1[q]}, l);
      l = __builtin_elementwise_fma(P2, v2f{qx2[q], qx2[q]}, l);
      l = __builtin_elementwise_fma(P3, v2f{qx3[q], qx3[q]}, l);
      const v2f e = v2f{EXP2F(l.x), EXP2F(l.y)};
      aV0[q] = __builtin_elementwise_fma(e, V0, aV0[q]);
      aV1[q] = __builtin_elementwise_fma(e, V1, aV1[q]);
      aV2[q] = __builtin_elementwise_fma(e, V2, aV2[q]);
      aV3[q] = __builtin_elementwise_fma(e, V3, aV3[q]);
      aD[q] += e;
    }
  };

#define LDCH(A_, B_, C_, D_, E_, it_) {                                  \
    const size_t o = (size_t)(pb + ((it_) << 6)) * 4;                    \
    A_ = *(const float4*)(feat + o);                                     \
    B_ = *(const float4*)(feat + (size_t)PLANE + o);                     \
    C_ = *(const float4*)(feat + (size_t)2*PLANE + o);                   \
    D_ = *(const float4*)(feat + (size_t)3*PLANE + o);                   \
    E_ = *(const float4*)(feat + (size_t)4*PLANE + o); }

  float4 pA, pB, pC, pD, pE;    // ping
  float4 nA, nB, nC, nD, nE;    // pong
  LDCH(pA, pB, pC, pD, pE, 0);
#pragma unroll
  for (int it = 0; it < 16; it += 2) {
    LDCH(nA, nB, nC, nD, nE, it + 1);      // issue odd-chunk loads early
    PROC(pA, pB, pC, pD, pE);              // compute even chunk
    if (it + 2 < 16) LDCH(pA, pB, pC, pD, pE, it + 2);
    PROC(nA, nB, nC, nD, nE);              // compute odd chunk
  }
#undef LDCH

  // horizontal (2 key-halves) + full-wave butterfly
  float s[QW][5];
#pragma unroll
  for (int q = 0; q < QW; ++q) {
    s[q][0] = aV0[q].x + aV0[q].y;
    s[q][1] = aV1[q].x + aV1[q].y;
    s[q][2] = aV2[q].x + aV2[q].y;
    s[q][3] = aV3[q].x + aV3[q].y;
    s[q][4] = aD[q].x + aD[q].y;
  }
#pragma unroll
  for (int q = 0; q < QW; ++q)
#pragma unroll
    for (int c = 0; c < 5; ++c) s[q][c] = wred64(s[q][c]);

  if (lane == 0) {
    float* dst = sums + wv*(QW*9);
#pragma unroll
    for (int q = 0; q < QW; ++q) {
#pragma unroll
      for (int c = 0; c < 5; ++c) dst[q*9 + c] = s[q][c];
    }
  }
  __syncthreads();

  // softmax normalize + residual + LN1 (token t = tid for tid<64; t matches wave*16+q)
  if (tid < 64) {
    const float* sv = sums + tid*9;
    const float inv = 1.0f / sv[4];
    const int gq = qbase + tid;
    float xv0, xv1, xv2, xv3;
    if (first) {
      xv0 = KEY[gq*3]; xv1 = KEY[gq*3+1]; xv2 = KEY[gq*3+2]; xv3 = VALUE[gq];
    } else {
      const float4 xv = *(const float4*)(X + (size_t)gq*4);
      xv0 = xv.x; xv1 = xv.y; xv2 = xv.z; xv3 = xv.w;
    }
    float t4[4];
    t4[0] = xv0 + fmaf(sv[0], inv, bo[0]);
    t4[1] = xv1 + fmaf(sv[1], inv, bo[1]);
    t4[2] = xv2 + fmaf(sv[2], inv, bo[2]);
    t4[3] = xv3 + fmaf(sv[3], inv, bo[3]);
    float r[4];
    ln4(t4, g1, be1, r);
    *(float4*)(ress + tid*4) = make_float4(r[0], r[1], r[2], r[3]);
  }
  __syncthreads();

  // FFN: fc = wave (4 chunks of 128 f), tok = lane
  const int tok = lane, fc = wv;
  const float4 rv = *(const float4*)(ress + tok*4);
  float fa0 = 0.f, fa1 = 0.f, fa2 = 0.f, fa3 = 0.f;
  const float* wt = w1t + (size_t)fc*128*12;
#pragma unroll 4
  for (int f = 0; f < 128; ++f) {
    const float* rec = wt + f*12;
    const float4 w1r = *(const float4*)rec;
    const float4 w2r = *(const float4*)(rec + 4);
    const float b1f = rec[8];
    float h = fmaf(rv.w, w1r.w, fmaf(rv.z, w1r.z, fmaf(rv.y, w1r.y, fmaf(rv.x, w1r.x, b1f))));
    h = fmaxf(h, 0.f);
    fa0 = fmaf(h, w2r.x, fa0);
    fa1 = fmaf(h, w2r.y, fa1);
    fa2 = fmaf(h, w2r.z, fa2);
    fa3 = fmaf(h, w2r.w, fa3);
  }
  *(float4*)(redf + (size_t)((fc << 6) + tok)*4) = make_float4(fa0, fa1, fa2, fa3);
  __syncthreads();

  // FFN reduce + residual + LN2 + output (X + next-layer feat planes, or final fc)
  if (tid < 64) {
    float t2[4];
#pragma unroll
    for (int c = 0; c < 4; ++c) {
      float sa = b2v[c];
#pragma unroll
      for (int k = 0; k < 4; ++k) sa += redf[(size_t)((k << 6) + tid)*4 + c];
      t2[c] = ress[tid*4 + c] + sa;
    }
    float y[4];
    ln4(t2, g2, be2, y);
    const int gq = qbase + tid;
    if (last) {
      outp[gq] = fmaf(y[3], Wfc[3], fmaf(y[2], Wfc[2], fmaf(y[1], Wfc[1], fmaf(y[0], Wfc[0], bfc[0]))));
    } else {
      *(float4*)(Xout + (size_t)gq*4) = make_float4(y[0], y[1], y[2], y[3]);
      float fr[9];
      compute_feat(y, smn, fr);
      const int p = gq >> 1, par = gq & 1;
#pragma unroll
      for (int c = 0; c < 8; ++c)
        featout[(size_t)(c >> 1)*PLANE + (size_t)p*4 + (c & 1)*2 + par] = fr[c];
      featout[(size_t)4*PLANE + (size_t)p*4 + par] = fr[8];
    }
  }
}

extern "C" void kernel_launch(void* const* d_in, const int* in_sizes, int n_in,
                              void* d_out, int out_size, void* d_ws, size_t ws_size,
                              hipStream_t stream)
{
  const float* KEY   = (const float*)d_in[0];
  const float* VALUE = (const float*)d_in[1];
  const float* Wq  = (const float*)d_in[2];
  const float* bq  = (const float*)d_in[3];
  const float* Wk  = (const float*)d_in[4];
  const float* bk  = (const float*)d_in[5];
  const float* Wv  = (const float*)d_in[6];
  const float* bv  = (const float*)d_in[7];
  const float* Wo  = (const float*)d_in[8];
  const float* bo  = (const float*)d_in[9];
  const float* bw  = (const float*)d_in[10];
  const float* g1  = (const float*)d_in[11];
  const float* be1 = (const float*)d_in[12];
  const float* W1  = (const float*)d_in[13];
  const float* b1  = (const float*)d_in[14];
  const float* W2  = (const float*)d_in[15];
  const float* b2  = (const float*)d_in[16];
  const float* g2  = (const float*)d_in[17];
  const float* be2 = (const float*)d_in[18];
  const float* Wfc = (const float*)d_in[19];
  const float* bfc = (const float*)d_in[20];
  float* out = (float*)d_out;

  float* w    = (float*)d_ws;
  float* sm   = w;              // 128
  float* w1t  = w + 128;        // 12288
  float* X1   = w + 12416;      // 131072
  float* f0   = w + 143488;     // 327680 (5 planes x 65536)
  float* f1   = w + 471168;     // 327680

  prep_kernel<<<2, 64, 0, stream>>>(Wq, bq, Wk, bk, Wv, bv, Wo, bw,
                                    W1, b1, W2, sm, w1t);
  feat_kernel<<<64, 256, 0, stream>>>(KEY, VALUE, sm, f0);

  // layer 0: queries/residual from KEY/VALUE, keys from f0; writes X1 + f1 (layer-1 sm)
  layer_kernel<<<512, 256, 0, stream>>>(KEY, VALUE, X1, f0,
      w1t, sm + 64,
      bo, g1, be1, b2, g2, be2,
      X1, f1, Wfc, bfc, out, 1, 0);

  // layer 1: consumes X1/f1, produces final output
  layer_kernel<<<512, 256, 0, stream>>>(KEY, VALUE, X1, f1,
      w1t + FF*12, sm,
      bo + 4, g1 + 4, be1 + 4, b2 + 4, g2 + 4, be2 + 4,
      X1, f1, Wfc, bfc, out, 0, 1);
}

// Round 8
// 187.216 us; speedup vs baseline: 1.0108x; 1.0108x over previous
//
#include <hip/hip_runtime.h>

#define BB 16
#define SS 2048
#define NTOK (BB*SS)
#define NPAIR (NTOK/2)
#define PLANE (NPAIR*4)
#define FF 512
#define EPSF 1e-5f
#define QW 8

#if __has_builtin(__builtin_amdgcn_exp2f)
#define EXP2F(x) __builtin_amdgcn_exp2f(x)
#else
#define EXP2F(x) exp2f(x)
#endif

typedef float v2f __attribute__((ext_vector_type(2)));

// ---------------- ws float layout ----------------
// sm   : [L][64]        fused small mats (exp2-prescaled)  @ 0        (128)
// w1t  : [L][512][12]   {w1col[4], w2row[4], b1, pad3}     @ 128      (12288)
// X1   : [NTOK][4]                                         @ 12416    (131072)
// f0   : [5][NPAIR][4]  pair-interleaved SoA planes        @ 143488   (327680)
// f1   : same                                              @ 471168   (327680)

__device__ __forceinline__ float wred64(float v) {
#pragma unroll
  for (int m = 32; m > 0; m >>= 1) v += __shfl_xor(v, m, 64);
  return v;
}

__device__ __forceinline__ float rflf(float v) {
  union { float f; int i; } u; u.f = v;
  u.i = __builtin_amdgcn_readfirstlane(u.i);
  return u.f;
}

// sm layout (per layer, stride 64):
// 0:M4[16] (bw2*Wq^T Wk)   16:Bk[16] (-.5 bw2 Wk^T Wk)   32:WVO[16] (Wv*Wo)
// 48:ak[4]  52:bvo[4]  56:ck      where bw2 = bw^2 * log2(e)

__global__ __launch_bounds__(64) void prep_kernel(
    const float* __restrict__ Wq, const float* __restrict__ bq,
    const float* __restrict__ Wk, const float* __restrict__ bk,
    const float* __restrict__ Wv, const float* __restrict__ bv,
    const float* __restrict__ Wo, const float* __restrict__ bw,
    const float* __restrict__ W1, const float* __restrict__ b1,
    const float* __restrict__ W2,
    float* __restrict__ sm, float* __restrict__ w1t)
{
  const int i = blockIdx.x;       // layer
  const int lane = threadIdx.x;   // 0..63
  float m4[4][4] = {{0}}, gkk[4][4] = {{0}}, wvo[4][4] = {{0}};
  float akk[4] = {0}, bvo[4] = {0};
  float ck1 = 0.f, ck2 = 0.f;

  for (int h = lane; h < 256; h += 64) {
    float vq[4], vk[4], vv[4], wo4[4];
#pragma unroll
    for (int a = 0; a < 4; ++a) {
      vq[a]  = Wq[(i*4 + a)*256 + h];
      vk[a]  = Wk[(i*4 + a)*256 + h];
      vv[a]  = Wv[(i*4 + a)*256 + h];
      wo4[a] = Wo[(i*256 + h)*4 + a];
    }
    const float bqh = bq[i*256 + h], bkh = bk[i*256 + h], bvh = bv[i*256 + h];
#pragma unroll
    for (int a = 0; a < 4; ++a) {
#pragma unroll
      for (int c = 0; c < 4; ++c) {
        m4[a][c]  = fmaf(vq[a], vk[c], m4[a][c]);
        gkk[a][c] = fmaf(vk[a], vk[c], gkk[a][c]);
        wvo[a][c] = fmaf(vv[a], wo4[c], wvo[a][c]);
      }
      akk[a] = fmaf(vk[a], bqh - bkh, akk[a]);
      bvo[a] = fmaf(bvh, wo4[a], bvo[a]);
    }
    ck1 = fmaf(bqh, bkh, ck1);
    ck2 = fmaf(bkh, bkh, ck2);
  }
#pragma unroll
  for (int a = 0; a < 4; ++a) {
#pragma unroll
    for (int c = 0; c < 4; ++c) {
      m4[a][c]  = wred64(m4[a][c]);
      gkk[a][c] = wred64(gkk[a][c]);
      wvo[a][c] = wred64(wvo[a][c]);
    }
    akk[a] = wred64(akk[a]);
    bvo[a] = wred64(bvo[a]);
  }
  ck1 = wred64(ck1); ck2 = wred64(ck2);

  if (lane == 0) {
    const float bwv = bw[i];
    const float bw2 = bwv * bwv * 1.44269504088896f;   // exp2 prescale
    float* s = sm + i*64;
#pragma unroll
    for (int a = 0; a < 4; ++a) {
#pragma unroll
      for (int c = 0; c < 4; ++c) {
        s[a*4+c]      = bw2 * m4[a][c];
        s[16 + a*4+c] = -0.5f * bw2 * gkk[a][c];
        s[32 + a*4+c] = wvo[a][c];
      }
      s[48+a] = bw2 * akk[a];
      s[52+a] = bvo[a];
    }
    s[56] = bw2 * (ck1 - 0.5f * ck2);
  }
  // FFN weight repack: w1t[f] = {W1[:,f], W2[f,:], b1[f], pad}
  for (int f = lane; f < FF; f += 64) {
    float* rec = w1t + (i*FF + f)*12;
#pragma unroll
    for (int c = 0; c < 4; ++c) rec[c]   = W1[(i*4 + c)*FF + f];
#pragma unroll
    for (int c = 0; c < 4; ++c) rec[4+c] = W2[(i*FF + f)*4 + c];
    rec[8] = b1[i*FF + f];
    rec[9] = 0.f; rec[10] = 0.f; rec[11] = 0.f;
  }
}

// feat record: {P[4], VT[4], R}; query-side constant dropped (cancels in softmax)
__device__ __forceinline__ void compute_feat(const float x[4], const float* __restrict__ s,
                                             float* __restrict__ featrec)
{
  float P[4], VT[4], tk[4];
#pragma unroll
  for (int a = 0; a < 4; ++a) {
    P[a]  = fmaf(s[a*4+3], x[3], fmaf(s[a*4+2], x[2], fmaf(s[a*4+1], x[1], s[a*4+0]*x[0])));
    tk[a] = fmaf(s[16+a*4+3], x[3], fmaf(s[16+a*4+2], x[2], fmaf(s[16+a*4+1], x[1], s[16+a*4+0]*x[0])));
    VT[a] = s[52+a] + fmaf(s[32+3*4+a], x[3], fmaf(s[32+2*4+a], x[2], fmaf(s[32+1*4+a], x[1], s[32+0*4+a]*x[0])));
  }
  float R = s[56];
#pragma unroll
  for (int a = 0; a < 4; ++a) R = fmaf(tk[a] + s[48+a], x[a], R);
  featrec[0]=P[0]; featrec[1]=P[1]; featrec[2]=P[2]; featrec[3]=P[3];
  featrec[4]=VT[0]; featrec[5]=VT[1]; featrec[6]=VT[2]; featrec[7]=VT[3];
  featrec[8]=R;
}

// layer-0 key features -> pair-interleaved SoA planes. thread = pair (2 tokens).
__global__ __launch_bounds__(256) void feat_kernel(
    const float* __restrict__ KEY, const float* __restrict__ VALUE,
    const float* __restrict__ sm, float* __restrict__ feat)
{
  const int p = blockIdx.x*256 + threadIdx.x;       // pair index
  const int ta = 2*p, tb = 2*p + 1;
  float xa[4] = {KEY[ta*3], KEY[ta*3+1], KEY[ta*3+2], VALUE[ta]};
  float xb[4] = {KEY[tb*3], KEY[tb*3+1], KEY[tb*3+2], VALUE[tb]};
  float fa[9], fb[9];
  compute_feat(xa, sm, fa);
  compute_feat(xb, sm, fb);
#pragma unroll
  for (int pl = 0; pl < 4; ++pl) {
    *(float4*)(feat + (size_t)pl*PLANE + (size_t)p*4) =
        make_float4(fa[2*pl], fb[2*pl], fa[2*pl+1], fb[2*pl+1]);
  }
  *(float4*)(feat + (size_t)4*PLANE + (size_t)p*4) =
      make_float4(fa[8], fb[8], 0.f, 0.f);
}

__device__ __forceinline__ void ln4(const float t[4], const float* __restrict__ g,
                                    const float* __restrict__ b, float r[4])
{
  const float m = 0.25f*(t[0]+t[1]+t[2]+t[3]);
  const float d0 = t[0]-m, d1 = t[1]-m, d2 = t[2]-m, d3 = t[3]-m;
  const float v = 0.25f*(d0*d0 + d1*d1 + d2*d2 + d3*d3);
  const float sc = rsqrtf(v + EPSF);
  r[0] = fmaf(d0*sc, g[0], b[0]);
  r[1] = fmaf(d1*sc, g[1], b[1]);
  r[2] = fmaf(d2*sc, g[2], b[2]);
  r[3] = fmaf(d3*sc, g[3], b[3]);
}

// Flipped-dataflow fused layer kernel, 8 q/wave, spill-proof:
// block = 256 thr (4 waves), 32 queries/block, grid 1024 = 4 blocks/CU
// (16 waves/CU at VGPR<=128). Wave owns 8 queries in SGPRs and streams all
// 2048 keys of its batch, 2 keys/lane from pair-interleaved SoA planes
// (coalesced float4; zero LDS / broadcast / barriers in the main loop).
// Single-buffered loads (acc 80 + buf 20 + temps ~20 <= 128: no AGPR shuffle,
// no scratch); latency hidden by 4 waves/SIMD TLP + unroll-4 pipelining.
// Epilogue: horizontal add + wave butterfly, LN1, FFN (8 fc x 64 f), LN2.
__global__ __launch_bounds__(256, 4) void layer_kernel(
    const float* __restrict__ KEY, const float* __restrict__ VALUE,
    const float* __restrict__ X, const float* __restrict__ feat,
    const float* __restrict__ w1t, const float* __restrict__ smn,
    const float* __restrict__ bo, const float* __restrict__ g1, const float* __restrict__ be1,
    const float* __restrict__ b2v, const float* __restrict__ g2, const float* __restrict__ be2,
    float* __restrict__ Xout, float* __restrict__ featout,
    const float* __restrict__ Wfc, const float* __restrict__ bfc,
    float* __restrict__ outp, int first, int last)
{
  const int bid = blockIdx.x;                  // 1024 blocks
  const int b = bid >> 6, qg = bid & 63;
  const int qbase = (b << 11) + (qg << 5);     // 32 queries per block
  const int tid = threadIdx.x;
  const int lane = tid & 63, wv = tid >> 6;    // wave 0..3
  const int q0 = qbase + wv*QW;                // this wave's 8 queries

  __shared__ float sums[4*QW*9];   // [wave][q][9] == [tok][9]
  __shared__ float ress[32*4];
  __shared__ float redf[8*32*4];

  // 8 queries -> SGPRs (uniform loads + readfirstlane)
  float qx0[QW], qx1[QW], qx2[QW], qx3[QW];
#pragma unroll
  for (int q = 0; q < QW; ++q) {
    const int gq = q0 + q;
    float a, b_, c, d;
    if (first) {
      a = KEY[gq*3]; b_ = KEY[gq*3+1]; c = KEY[gq*3+2]; d = VALUE[gq];
    } else {
      const float4 xv = *(const float4*)(X + (size_t)gq*4);
      a = xv.x; b_ = xv.y; c = xv.z; d = xv.w;
    }
    qx0[q] = rflf(a); qx1[q] = rflf(b_); qx2[q] = rflf(c); qx3[q] = rflf(d);
  }

  v2f aV0[QW], aV1[QW], aV2[QW], aV3[QW], aD[QW];
#pragma unroll
  for (int q = 0; q < QW; ++q) {
    aV0[q] = v2f{0.f,0.f}; aV1[q] = v2f{0.f,0.f};
    aV2[q] = v2f{0.f,0.f}; aV3[q] = v2f{0.f,0.f};
    aD[q]  = v2f{0.f,0.f};
  }

  // key stream: 16 iters x 128 keys (2 packed keys per lane), single-buffered
  const int pb = (b << 10) + lane;             // batch pair base + lane
#pragma unroll 4
  for (int it = 0; it < 16; ++it) {
    const size_t o = (size_t)(pb + (it << 6)) * 4;
    const float4 A  = *(const float4*)(feat + o);                     // P0a,P0b,P1a,P1b
    const float4 Bf = *(const float4*)(feat + (size_t)PLANE + o);     // P2a,P2b,P3a,P3b
    const float4 C  = *(const float4*)(feat + (size_t)2*PLANE + o);   // V0a,V0b,V1a,V1b
    const float4 D  = *(const float4*)(feat + (size_t)3*PLANE + o);   // V2a,V2b,V3a,V3b
    const float4 E  = *(const float4*)(feat + (size_t)4*PLANE + o);   // Ra,Rb,-,-
    const v2f P0 = v2f{A.x, A.y},   P1 = v2f{A.z, A.w};
    const v2f P2 = v2f{Bf.x, Bf.y}, P3 = v2f{Bf.z, Bf.w};
    const v2f V0 = v2f{C.x, C.y},   V1 = v2f{C.z, C.w};
    const v2f V2 = v2f{D.x, D.y},   V3 = v2f{D.z, D.w};
    const v2f Rp = v2f{E.x, E.y};
#pragma unroll
    for (int q = 0; q < QW; ++q) {
      v2f l = __builtin_elementwise_fma(P0, v2f{qx0[q], qx0[q]}, Rp);
      l = __builtin_elementwise_fma(P1, v2f{qx1[q], qx1[q]}, l);
      l = __builtin_elementwise_fma(P2, v2f{qx2[q], qx2[q]}, l);
      l = __builtin_elementwise_fma(P3, v2f{qx3[q], qx3[q]}, l);
      const v2f e = v2f{EXP2F(l.x), EXP2F(l.y)};
      aV0[q] = __builtin_elementwise_fma(e, V0, aV0[q]);
      aV1[q] = __builtin_elementwise_fma(e, V1, aV1[q]);
      aV2[q] = __builtin_elementwise_fma(e, V2, aV2[q]);
      aV3[q] = __builtin_elementwise_fma(e, V3, aV3[q]);
      aD[q] += e;
    }
  }

  // horizontal (2 key-halves) + full-wave butterfly
  float s[QW][5];
#pragma unroll
  for (int q = 0; q < QW; ++q) {
    s[q][0] = aV0[q].x + aV0[q].y;
    s[q][1] = aV1[q].x + aV1[q].y;
    s[q][2] = aV2[q].x + aV2[q].y;
    s[q][3] = aV3[q].x + aV3[q].y;
    s[q][4] = aD[q].x + aD[q].y;
  }
#pragma unroll
  for (int q = 0; q < QW; ++q)
#pragma unroll
    for (int c = 0; c < 5; ++c) s[q][c] = wred64(s[q][c]);

  if (lane == 0) {
    float* dst = sums + wv*(QW*9);
#pragma unroll
    for (int q = 0; q < QW; ++q) {
#pragma unroll
      for (int c = 0; c < 5; ++c) dst[q*9 + c] = s[q][c];
    }
  }
  __syncthreads();

  // softmax normalize + residual + LN1 (token t = tid for tid<32; t == wv*8+q)
  if (tid < 32) {
    const float* sv = sums + tid*9;
    const float inv = 1.0f / sv[4];
    const int gq = qbase + tid;
    float xv0, xv1, xv2, xv3;
    if (first) {
      xv0 = KEY[gq*3]; xv1 = KEY[gq*3+1]; xv2 = KEY[gq*3+2]; xv3 = VALUE[gq];
    } else {
      const float4 xv = *(const float4*)(X + (size_t)gq*4);
      xv0 = xv.x; xv1 = xv.y; xv2 = xv.z; xv3 = xv.w;
    }
    float t4[4];
    t4[0] = xv0 + fmaf(sv[0], inv, bo[0]);
    t4[1] = xv1 + fmaf(sv[1], inv, bo[1]);
    t4[2] = xv2 + fmaf(sv[2], inv, bo[2]);
    t4[3] = xv3 + fmaf(sv[3], inv, bo[3]);
    float r[4];
    ln4(t4, g1, be1, r);
    *(float4*)(ress + tid*4) = make_float4(r[0], r[1], r[2], r[3]);
  }
  __syncthreads();

  // FFN: tok = tid&31 (32 tokens), fc = tid>>5 (8 chunks of 64 f)
  const int tok = tid & 31, fc = tid >> 5;
  const float4 rv = *(const float4*)(ress + tok*4);
  float fa0 = 0.f, fa1 = 0.f, fa2 = 0.f, fa3 = 0.f;
  const float* wt = w1t + (size_t)fc*64*12;
#pragma unroll 4
  for (int f = 0; f < 64; ++f) {
    const float* rec = wt + f*12;
    const float4 w1r = *(const float4*)rec;
    const float4 w2r = *(const float4*)(rec + 4);
    const float b1f = rec[8];
    float h = fmaf(rv.w, w1r.w, fmaf(rv.z, w1r.z, fmaf(rv.y, w1r.y, fmaf(rv.x, w1r.x, b1f))));
    h = fmaxf(h, 0.f);
    fa0 = fmaf(h, w2r.x, fa0);
    fa1 = fmaf(h, w2r.y, fa1);
    fa2 = fmaf(h, w2r.z, fa2);
    fa3 = fmaf(h, w2r.w, fa3);
  }
  *(float4*)(redf + (size_t)((fc << 5) + tok)*4) = make_float4(fa0, fa1, fa2, fa3);
  __syncthreads();

  // FFN reduce + residual + LN2 + output (X + next-layer feat planes, or final fc)
  if (tid < 32) {
    float t2[4];
#pragma unroll
    for (int c = 0; c < 4; ++c) {
      float sa = b2v[c];
#pragma unroll
      for (int k = 0; k < 8; ++k) sa += redf[(size_t)((k << 5) + tid)*4 + c];
      t2[c] = ress[tid*4 + c] + sa;
    }
    float y[4];
    ln4(t2, g2, be2, y);
    const int gq = qbase + tid;
    if (last) {
      outp[gq] = fmaf(y[3], Wfc[3], fmaf(y[2], Wfc[2], fmaf(y[1], Wfc[1], fmaf(y[0], Wfc[0], bfc[0]))));
    } else {
      *(float4*)(Xout + (size_t)gq*4) = make_float4(y[0], y[1], y[2], y[3]);
      float fr[9];
      compute_feat(y, smn, fr);
      const int p = gq >> 1, par = gq & 1;
#pragma unroll
      for (int c = 0; c < 8; ++c)
        featout[(size_t)(c >> 1)*PLANE + (size_t)p*4 + (c & 1)*2 + par] = fr[c];
      featout[(size_t)4*PLANE + (size_t)p*4 + par] = fr[8];
    }
  }
}

extern "C" void kernel_launch(void* const* d_in, const int* in_sizes, int n_in,
                              void* d_out, int out_size, void* d_ws, size_t ws_size,
                              hipStream_t stream)
{
  const float* KEY   = (const float*)d_in[0];
  const float* VALUE = (const float*)d_in[1];
  const float* Wq  = (const float*)d_in[2];
  const float* bq  = (const float*)d_in[3];
  const float* Wk  = (const float*)d_in[4];
  const float* bk  = (const float*)d_in[5];
  const float* Wv  = (const float*)d_in[6];
  const float* bv  = (const float*)d_in[7];
  const float* Wo  = (const float*)d_in[8];
  const float* bo  = (const float*)d_in[9];
  const float* bw  = (const float*)d_in[10];
  const float* g1  = (const float*)d_in[11];
  const float* be1 = (const float*)d_in[12];
  const float* W1  = (const float*)d_in[13];
  const float* b1  = (const float*)d_in[14];
  const float* W2  = (const float*)d_in[15];
  const float* b2  = (const float*)d_in[16];
  const float* g2  = (const float*)d_in[17];
  const float* be2 = (const float*)d_in[18];
  const float* Wfc = (const float*)d_in[19];
  const float* bfc = (const float*)d_in[20];
  float* out = (float*)d_out;

  float* w    = (float*)d_ws;
  float* sm   = w;              // 128
  float* w1t  = w + 128;        // 12288
  float* X1   = w + 12416;      // 131072
  float* f0   = w + 143488;     // 327680 (5 planes x 65536)
  float* f1   = w + 471168;     // 327680

  prep_kernel<<<2, 64, 0, stream>>>(Wq, bq, Wk, bk, Wv, bv, Wo, bw,
                                    W1, b1, W2, sm, w1t);
  feat_kernel<<<64, 256, 0, stream>>>(KEY, VALUE, sm, f0);

  // layer 0: queries/residual from KEY/VALUE, keys from f0; writes X1 + f1 (layer-1 sm)
  layer_kernel<<<1024, 256, 0, stream>>>(KEY, VALUE, X1, f0,
      w1t, sm + 64,
      bo, g1, be1, b2, g2, be2,
      X1, f1, Wfc, bfc, out, 1, 0);

  // layer 1: consumes X1/f1, produces final output
  layer_kernel<<<1024, 256, 0, stream>>>(KEY, VALUE, X1, f1,
      w1t + FF*12, sm,
      bo + 4, g1 + 4, be1 + 4, b2 + 4, g2 + 4, be2 + 4,
      X1, f1, Wfc, bfc, out, 0, 1);
}

// Round 10
// 161.997 us; speedup vs baseline: 1.1681x; 1.1557x over previous
//
#include <hip/hip_runtime.h>

#define BB 16
#define SS 2048
#define NTOK (BB*SS)
#define NPAIR (NTOK/2)
#define FF 512
#define EPSF 1e-5f
#define QW 4

#if __has_builtin(__builtin_amdgcn_exp2f)
#define EXP2F(x) __builtin_amdgcn_exp2f(x)
#else
#define EXP2F(x) exp2f(x)
#endif

typedef float v2f __attribute__((ext_vector_type(2)));

// ---------------- ws float layout ----------------
// sm   : [L][64]        fused small mats (exp2-prescaled)  @ 0        (128)
// w1t  : [L][512][12]   {w1col[4], w2row[4], b1, pad3}     @ 128      (12288)
// X1   : [NTOK][4]                                         @ 12416    (131072)
// f0XA : [NPAIR][4]  {x0a,x0b,x1a,x1b}                     @ 143488   (65536)
// f0XB : [NPAIR][4]  {x2a,x2b,x3a,x3b}                     @ 209024   (65536)
// f0RR : [NPAIR][2]  {Ra,Rb}                               @ 274560   (32768)
// f1XA/XB/RR: same                                         @ 307328 / 372864 / 438400

__device__ __forceinline__ float wred64(float v) {
#pragma unroll
  for (int m = 32; m > 0; m >>= 1) v += __shfl_xor(v, m, 64);
  return v;
}

__device__ __forceinline__ float rflf(float v) {
  union { float f; int i; } u; u.f = v;
  u.i = __builtin_amdgcn_readfirstlane(u.i);
  return u.f;
}

// sm layout (per layer, stride 64):
// 0:M4[16] (bw2*Wq^T Wk)   16:Bk[16] (-.5 bw2 Wk^T Wk)   32:WVO[16] (Wv*Wo)
// 48:ak[4]  52:bvo[4]  56:ck      where bw2 = bw^2 * log2(e)

__global__ __launch_bounds__(64) void prep_kernel(
    const float* __restrict__ Wq, const float* __restrict__ bq,
    const float* __restrict__ Wk, const float* __restrict__ bk,
    const float* __restrict__ Wv, const float* __restrict__ bv,
    const float* __restrict__ Wo, const float* __restrict__ bw,
    const float* __restrict__ W1, const float* __restrict__ b1,
    const float* __restrict__ W2,
    float* __restrict__ sm, float* __restrict__ w1t)
{
  const int i = blockIdx.x;       // layer
  const int lane = threadIdx.x;   // 0..63
  float m4[4][4] = {{0}}, gkk[4][4] = {{0}}, wvo[4][4] = {{0}};
  float akk[4] = {0}, bvo[4] = {0};
  float ck1 = 0.f, ck2 = 0.f;

  for (int h = lane; h < 256; h += 64) {
    float vq[4], vk[4], vv[4], wo4[4];
#pragma unroll
    for (int a = 0; a < 4; ++a) {
      vq[a]  = Wq[(i*4 + a)*256 + h];
      vk[a]  = Wk[(i*4 + a)*256 + h];
      vv[a]  = Wv[(i*4 + a)*256 + h];
      wo4[a] = Wo[(i*256 + h)*4 + a];
    }
    const float bqh = bq[i*256 + h], bkh = bk[i*256 + h], bvh = bv[i*256 + h];
#pragma unroll
    for (int a = 0; a < 4; ++a) {
#pragma unroll
      for (int c = 0; c < 4; ++c) {
        m4[a][c]  = fmaf(vq[a], vk[c], m4[a][c]);
        gkk[a][c] = fmaf(vk[a], vk[c], gkk[a][c]);
        wvo[a][c] = fmaf(vv[a], wo4[c], wvo[a][c]);
      }
      akk[a] = fmaf(vk[a], bqh - bkh, akk[a]);
      bvo[a] = fmaf(bvh, wo4[a], bvo[a]);
    }
    ck1 = fmaf(bqh, bkh, ck1);
    ck2 = fmaf(bkh, bkh, ck2);
  }
#pragma unroll
  for (int a = 0; a < 4; ++a) {
#pragma unroll
    for (int c = 0; c < 4; ++c) {
      m4[a][c]  = wred64(m4[a][c]);
      gkk[a][c] = wred64(gkk[a][c]);
      wvo[a][c] = wred64(wvo[a][c]);
    }
    akk[a] = wred64(akk[a]);
    bvo[a] = wred64(bvo[a]);
  }
  ck1 = wred64(ck1); ck2 = wred64(ck2);

  if (lane == 0) {
    const float bwv = bw[i];
    const float bw2 = bwv * bwv * 1.44269504088896f;   // exp2 prescale
    float* s = sm + i*64;
#pragma unroll
    for (int a = 0; a < 4; ++a) {
#pragma unroll
      for (int c = 0; c < 4; ++c) {
        s[a*4+c]      = bw2 * m4[a][c];
        s[16 + a*4+c] = -0.5f * bw2 * gkk[a][c];
        s[32 + a*4+c] = wvo[a][c];
      }
      s[48+a] = bw2 * akk[a];
      s[52+a] = bvo[a];
    }
    s[56] = bw2 * (ck1 - 0.5f * ck2);
  }
  // FFN weight repack: w1t[f] = {W1[:,f], W2[f,:], b1[f], pad}
  for (int f = lane; f < FF; f += 64) {
    float* rec = w1t + (i*FF + f)*12;
#pragma unroll
    for (int c = 0; c < 4; ++c) rec[c]   = W1[(i*4 + c)*FF + f];
#pragma unroll
    for (int c = 0; c < 4; ++c) rec[4+c] = W2[(i*FF + f)*4 + c];
    rec[8] = b1[i*FF + f];
    rec[9] = 0.f; rec[10] = 0.f; rec[11] = 0.f;
  }
}

// R(x) = ck + sum_a (Bk x + ak)[a] * x[a]  (the key-side quadratic+linear logit part)
__device__ __forceinline__ float compute_R(const float x[4], const float* __restrict__ s)
{
  float R = s[56];
#pragma unroll
  for (int a = 0; a < 4; ++a) {
    const float tk = fmaf(s[16+a*4+3], x[3], fmaf(s[16+a*4+2], x[2],
                     fmaf(s[16+a*4+1], x[1], s[16+a*4+0]*x[0])));
    R = fmaf(tk + s[48+a], x[a], R);
  }
  return R;
}

// layer-0 key planes from KEY/VALUE. thread = pair (2 tokens).
__global__ __launch_bounds__(256) void feat_kernel(
    const float* __restrict__ KEY, const float* __restrict__ VALUE,
    const float* __restrict__ sm,
    float* __restrict__ fXA, float* __restrict__ fXB, float* __restrict__ fRR)
{
  const int p = blockIdx.x*256 + threadIdx.x;       // pair index
  const int ta = 2*p, tb = 2*p + 1;
  float xa[4] = {KEY[ta*3], KEY[ta*3+1], KEY[ta*3+2], VALUE[ta]};
  float xb[4] = {KEY[tb*3], KEY[tb*3+1], KEY[tb*3+2], VALUE[tb]};
  const float Ra = compute_R(xa, sm), Rb = compute_R(xb, sm);
  *(float4*)(fXA + (size_t)p*4) = make_float4(xa[0], xb[0], xa[1], xb[1]);
  *(float4*)(fXB + (size_t)p*4) = make_float4(xa[2], xb[2], xa[3], xb[3]);
  *(v2f*)(fRR + (size_t)p*2) = v2f{Ra, Rb};
}

__device__ __forceinline__ void ln4(const float t[4], const float* __restrict__ g,
                                    const float* __restrict__ b, float r[4])
{
  const float m = 0.25f*(t[0]+t[1]+t[2]+t[3]);
  const float d0 = t[0]-m, d1 = t[1]-m, d2 = t[2]-m, d3 = t[3]-m;
  const float v = 0.25f*(d0*d0 + d1*d1 + d2*d2 + d3*d3);
  const float sc = rsqrtf(v + EPSF);
  r[0] = fmaf(d0*sc, g[0], b[0]);
  r[1] = fmaf(d1*sc, g[1], b[1]);
  r[2] = fmaf(d2*sc, g[2], b[2]);
  r[3] = fmaf(d3*sc, g[3], b[3]);
}

// Fused layer kernel, linear-V factorization:
//   l(q,k) = g_q . x_k + R(k),  g_q = M4^T x_q  (SGPR, per wave)
//   attn accumulates only {sum e*x_k (4), sum e} -> Wvo applied once per token.
// Key stream = {x[4], R} (5 floats): 3 LDS reads per 2 keys (2xb128 + 1xb64).
// Block = 512 thr (8 waves x 4 q = 32 q), grid 1024 = 64 blocks/batch;
// VGPR <= 64 (acc 40 + temps) -> 8 waves/SIMD FULL occupancy, no AGPR/scratch.
// Keys staged per-block in LDS, 2 chunks x 512 pairs (20 KB, per-lane reads).
__global__ __launch_bounds__(512, 8) void layer_kernel(
    const float* __restrict__ KEY, const float* __restrict__ VALUE,
    const float* __restrict__ X,
    const float* __restrict__ fXA, const float* __restrict__ fXB, const float* __restrict__ fRR,
    const float* __restrict__ w1t, const float* __restrict__ smc, const float* __restrict__ smn,
    const float* __restrict__ bo, const float* __restrict__ g1, const float* __restrict__ be1,
    const float* __restrict__ b2v, const float* __restrict__ g2, const float* __restrict__ be2,
    float* __restrict__ Xout,
    float* __restrict__ foXA, float* __restrict__ foXB, float* __restrict__ foRR,
    const float* __restrict__ Wfc, const float* __restrict__ bfc,
    float* __restrict__ outp, int first, int last)
{
  const int bid = blockIdx.x;                  // 1024 blocks = 16 batches x 64
  const int b = bid >> 6, qg = bid & 63;       // FIXED (R9 bug: was >>5 / &31)
  const int qbase = (b << 11) + (qg << 5);     // 32 queries per block
  const int tid = threadIdx.x;
  const int lane = tid & 63, wv = tid >> 6;    // 8 waves
  const int q0 = qbase + wv*QW;                // this wave's 4 queries

  __shared__ float smem[5120];   // 20 KB arena
  float* sXA = smem;             // [512][4]
  float* sXB = smem + 2048;      // [512][4]
  float* sRR = smem + 4096;      // [512][2]
  // scratch aliases (valid only after the final compute barrier):
  float* sums = smem;            // [32][6]
  float* ress = smem + 256;      // [32][4]
  float* redf = smem + 512;      // [16][32][4] = 2048

  // q side: g_q = M4^T x_q  -> SGPRs
  float gv0[QW], gv1[QW], gv2[QW], gv3[QW];
#pragma unroll
  for (int q = 0; q < QW; ++q) {
    const int gq = q0 + q;
    float x0, x1, x2, x3;
    if (first) {
      x0 = KEY[gq*3]; x1 = KEY[gq*3+1]; x2 = KEY[gq*3+2]; x3 = VALUE[gq];
    } else {
      const float4 xv = *(const float4*)(X + (size_t)gq*4);
      x0 = xv.x; x1 = xv.y; x2 = xv.z; x3 = xv.w;
    }
    // g[c] = sum_a smc[a*4+c] * x[a]
    float g0 = fmaf(smc[12], x3, fmaf(smc[ 8], x2, fmaf(smc[4], x1, smc[0]*x0)));
    float g1_ = fmaf(smc[13], x3, fmaf(smc[ 9], x2, fmaf(smc[5], x1, smc[1]*x0)));
    float g2_ = fmaf(smc[14], x3, fmaf(smc[10], x2, fmaf(smc[6], x1, smc[2]*x0)));
    float g3_ = fmaf(smc[15], x3, fmaf(smc[11], x2, fmaf(smc[7], x1, smc[3]*x0)));
    gv0[q] = rflf(g0); gv1[q] = rflf(g1_); gv2[q] = rflf(g2_); gv3[q] = rflf(g3_);
  }

  v2f aX0[QW], aX1[QW], aX2[QW], aX3[QW], aD[QW];
#pragma unroll
  for (int q = 0; q < QW; ++q) {
    aX0[q] = v2f{0.f,0.f}; aX1[q] = v2f{0.f,0.f};
    aX2[q] = v2f{0.f,0.f}; aX3[q] = v2f{0.f,0.f};
    aD[q]  = v2f{0.f,0.f};
  }

  const int pbb = b << 10;                     // 1024 pairs per batch
#pragma unroll
  for (int c = 0; c < 2; ++c) {
    // stage chunk c (512 pairs): issue loads, wait for prev compute, write LDS
    {
      const int gp = pbb + c*512 + tid;
      const float4 va = *(const float4*)(fXA + (size_t)gp*4);
      const float4 vb = *(const float4*)(fXB + (size_t)gp*4);
      const v2f    vr = *(const v2f*)(fRR + (size_t)gp*2);
      __syncthreads();                         // buffer free (no-op for c=0)
      *(float4*)(sXA + tid*4) = va;
      *(float4*)(sXB + tid*4) = vb;
      *(v2f*)(sRR + tid*2) = vr;
      __syncthreads();
    }
#pragma unroll 2
    for (int it = 0; it < 8; ++it) {
      const int p = lane + (it << 6);
      const float4 XAv = *(const float4*)(sXA + p*4);
      const float4 XBv = *(const float4*)(sXB + p*4);
      const v2f   RRv = *(const v2f*)(sRR + p*2);
      const v2f X0 = v2f{XAv.x, XAv.y}, X1 = v2f{XAv.z, XAv.w};
      const v2f X2 = v2f{XBv.x, XBv.y}, X3 = v2f{XBv.z, XBv.w};
#pragma unroll
      for (int q = 0; q < QW; ++q) {
        v2f l = __builtin_elementwise_fma(X0, v2f{gv0[q], gv0[q]}, RRv);
        l = __builtin_elementwise_fma(X1, v2f{gv1[q], gv1[q]}, l);
        l = __builtin_elementwise_fma(X2, v2f{gv2[q], gv2[q]}, l);
        l = __builtin_elementwise_fma(X3, v2f{gv3[q], gv3[q]}, l);
        const v2f e = v2f{EXP2F(l.x), EXP2F(l.y)};
        aX0[q] = __builtin_elementwise_fma(e, X0, aX0[q]);
        aX1[q] = __builtin_elementwise_fma(e, X1, aX1[q]);
        aX2[q] = __builtin_elementwise_fma(e, X2, aX2[q]);
        aX3[q] = __builtin_elementwise_fma(e, X3, aX3[q]);
        aD[q] += e;
      }
    }
  }
  __syncthreads();                             // key buffer dead; scratch aliasing OK

  // horizontal (even/odd keys) + full-wave butterfly; lane0 stores per-q sums
  {
    float s[QW][5];
#pragma unroll
    for (int q = 0; q < QW; ++q) {
      s[q][0] = aX0[q].x + aX0[q].y;
      s[q][1] = aX1[q].x + aX1[q].y;
      s[q][2] = aX2[q].x + aX2[q].y;
      s[q][3] = aX3[q].x + aX3[q].y;
      s[q][4] = aD[q].x + aD[q].y;
    }
#pragma unroll
    for (int q = 0; q < QW; ++q)
#pragma unroll
      for (int c = 0; c < 5; ++c) s[q][c] = wred64(s[q][c]);
    if (lane == 0) {
#pragma unroll
      for (int q = 0; q < QW; ++q) {
        float* dst = sums + (wv*QW + q)*6;
#pragma unroll
        for (int c = 0; c < 5; ++c) dst[c] = s[q][c];
      }
    }
  }
  __syncthreads();

  // softmax normalize + Wvo projection + residual + LN1 (token t = tid for tid<32)
  if (tid < 32) {
    const float* sv = sums + tid*6;
    const float inv = 1.0f / sv[4];
    const float m0 = sv[0]*inv, m1 = sv[1]*inv, m2 = sv[2]*inv, m3 = sv[3]*inv;
    const int gq = qbase + tid;
    float xv0, xv1, xv2, xv3;
    if (first) {
      xv0 = KEY[gq*3]; xv1 = KEY[gq*3+1]; xv2 = KEY[gq*3+2]; xv3 = VALUE[gq];
    } else {
      const float4 xv = *(const float4*)(X + (size_t)gq*4);
      xv0 = xv.x; xv1 = xv.y; xv2 = xv.z; xv3 = xv.w;
    }
    float t4[4];
#pragma unroll
    for (int a = 0; a < 4; ++a) {
      // attn[a] = bvo[a] + sum_c wvo[c][a]*m[c];  wvo at smc[32+c*4+a]
      float at = smc[52+a];
      at = fmaf(smc[32+0*4+a], m0, at);
      at = fmaf(smc[32+1*4+a], m1, at);
      at = fmaf(smc[32+2*4+a], m2, at);
      at = fmaf(smc[32+3*4+a], m3, at);
      const float xr = (a==0) ? xv0 : (a==1) ? xv1 : (a==2) ? xv2 : xv3;
      t4[a] = xr + at + bo[a];
    }
    float r[4];
    ln4(t4, g1, be1, r);
    *(float4*)(ress + tid*4) = make_float4(r[0], r[1], r[2], r[3]);
  }
  __syncthreads();

  // FFN: tok = tid&31 (32 tokens), fc = tid>>5 (16 chunks of 32 f)
  const int tok = tid & 31, fc = tid >> 5;
  const float4 rv = *(const float4*)(ress + tok*4);
  float fa0 = 0.f, fa1 = 0.f, fa2 = 0.f, fa3 = 0.f;
  const float* wt = w1t + (size_t)fc*32*12;
#pragma unroll 4
  for (int f = 0; f < 32; ++f) {
    const float* rec = wt + f*12;
    const float4 w1r = *(const float4*)rec;
    const float4 w2r = *(const float4*)(rec + 4);
    const float b1f = rec[8];
    float h = fmaf(rv.w, w1r.w, fmaf(rv.z, w1r.z, fmaf(rv.y, w1r.y, fmaf(rv.x, w1r.x, b1f))));
    h = fmaxf(h, 0.f);
    fa0 = fmaf(h, w2r.x, fa0);
    fa1 = fmaf(h, w2r.y, fa1);
    fa2 = fmaf(h, w2r.z, fa2);
    fa3 = fmaf(h, w2r.w, fa3);
  }
  *(float4*)(redf + (size_t)((fc << 5) + tok)*4) = make_float4(fa0, fa1, fa2, fa3);
  __syncthreads();

  // FFN reduce + residual + LN2 + output (X + next-layer planes, or final fc)
  if (tid < 32) {
    float t2[4];
#pragma unroll
    for (int c = 0; c < 4; ++c) {
      float sa = b2v[c];
#pragma unroll
      for (int k = 0; k < 16; ++k) sa += redf[(size_t)((k << 5) + tid)*4 + c];
      t2[c] = ress[tid*4 + c] + sa;
    }
    float y[4];
    ln4(t2, g2, be2, y);
    const int gq = qbase + tid;
    if (last) {
      outp[gq] = fmaf(y[3], Wfc[3], fmaf(y[2], Wfc[2], fmaf(y[1], Wfc[1], fmaf(y[0], Wfc[0], bfc[0]))));
    } else {
      *(float4*)(Xout + (size_t)gq*4) = make_float4(y[0], y[1], y[2], y[3]);
      const float Rn = compute_R(y, smn);
      const int p = gq >> 1, par = gq & 1;
      foXA[(size_t)p*4 + par]     = y[0];
      foXA[(size_t)p*4 + 2 + par] = y[1];
      foXB[(size_t)p*4 + par]     = y[2];
      foXB[(size_t)p*4 + 2 + par] = y[3];
      foRR[(size_t)p*2 + par]     = Rn;
    }
  }
}

extern "C" void kernel_launch(void* const* d_in, const int* in_sizes, int n_in,
                              void* d_out, int out_size, void* d_ws, size_t ws_size,
                              hipStream_t stream)
{
  const float* KEY   = (const float*)d_in[0];
  const float* VALUE = (const float*)d_in[1];
  const float* Wq  = (const float*)d_in[2];
  const float* bq  = (const float*)d_in[3];
  const float* Wk  = (const float*)d_in[4];
  const float* bk  = (const float*)d_in[5];
  const float* Wv  = (const float*)d_in[6];
  const float* bv  = (const float*)d_in[7];
  const float* Wo  = (const float*)d_in[8];
  const float* bo  = (const float*)d_in[9];
  const float* bw  = (const float*)d_in[10];
  const float* g1  = (const float*)d_in[11];
  const float* be1 = (const float*)d_in[12];
  const float* W1  = (const float*)d_in[13];
  const float* b1  = (const float*)d_in[14];
  const float* W2  = (const float*)d_in[15];
  const float* b2  = (const float*)d_in[16];
  const float* g2  = (const float*)d_in[17];
  const float* be2 = (const float*)d_in[18];
  const float* Wfc = (const float*)d_in[19];
  const float* bfc = (const float*)d_in[20];
  float* out = (float*)d_out;

  float* w    = (float*)d_ws;
  float* sm   = w;              // 128
  float* w1t  = w + 128;        // 12288
  float* X1   = w + 12416;      // 131072
  float* f0XA = w + 143488;     // 65536
  float* f0XB = w + 209024;     // 65536
  float* f0RR = w + 274560;     // 32768
  float* f1XA = w + 307328;     // 65536
  float* f1XB = w + 372864;     // 65536
  float* f1RR = w + 438400;     // 32768

  prep_kernel<<<2, 64, 0, stream>>>(Wq, bq, Wk, bk, Wv, bv, Wo, bw,
                                    W1, b1, W2, sm, w1t);
  feat_kernel<<<64, 256, 0, stream>>>(KEY, VALUE, sm, f0XA, f0XB, f0RR);

  // layer 0: queries/residual from KEY/VALUE, keys from f0 planes;
  // writes X1 + f1 planes (R via layer-1 sm)
  layer_kernel<<<1024, 512, 0, stream>>>(KEY, VALUE, X1, f0XA, f0XB, f0RR,
      w1t, sm, sm + 64,
      bo, g1, be1, b2, g2, be2,
      X1, f1XA, f1XB, f1RR, Wfc, bfc, out, 1, 0);

  // layer 1: consumes X1/f1 planes, produces final output
  layer_kernel<<<1024, 512, 0, stream>>>(KEY, VALUE, X1, f1XA, f1XB, f1RR,
      w1t + FF*12, sm + 64, sm,
      bo + 4, g1 + 4, be1 + 4, b2 + 4, g2 + 4, be2 + 4,
      X1, f1XA, f1XB, f1RR, Wfc, bfc, out, 0, 1);
}